// Round 11
// baseline (246.408 us; speedup 1.0000x reference)
//
#include <hip/hip_runtime.h>

#define NN 50000
#define NE 800000
#define DD 128
#define BUCKETS 196   // ceil(NN/256) buckets of 256 nodes
#define PB 4096       // edges per partition block
#define PBLK 196      // ceil(NE/PB)
#define EMAX 6144     // per-bucket edge cap (mean 4096, sigma 64 -> +32 sigma)
#define PACKB 6250    // x-pack blocks: NN*DD/4/256
#define MPAD 136      // ushorts per row in LDS mean tile / per col in sB half

typedef unsigned int uint_t;
typedef unsigned short ush_t;
typedef __attribute__((ext_vector_type(8))) short short8;   // 8 bf16
typedef __attribute__((ext_vector_type(4))) float f32x4;    // MFMA C/D

// bf16 helpers
__device__ __forceinline__ float bflo(uint_t u) { return __uint_as_float(u << 16); }
__device__ __forceinline__ float bfhi(uint_t u) { return __uint_as_float(u & 0xffff0000u); }
__device__ __forceinline__ ush_t f2bf(float f) {  // RNE
  uint_t u = __float_as_uint(f);
  u += 0x7fffu + ((u >> 16) & 1u);
  return (ush_t)(u >> 16);
}
__device__ __forceinline__ uint_t pack2(float a, float b) {
  return (uint_t)f2bf(a) | ((uint_t)f2bf(b) << 16);
}

__device__ __forceinline__ int ld_idx(const void* ei, int is64, long long i) {
  return is64 ? (int)((const long long*)ei)[i] : ((const int*)ei)[i];
}

// Per-wave inline index-width detect (u64 view of int32 pairs has nonzero
// high words within the first 64 entries; true int64 indices < 50000 don't).
__device__ __forceinline__ int detect64(const void* ei) {
  const unsigned long long* p = (const unsigned long long*)ei;
  unsigned long long w = p[threadIdx.x & 63];
  return __ballot((w >> 32) != 0) == 0ull ? 1 : 0;
}

// Block-wide inclusive scan over 256 ints.
__device__ __forceinline__ int block_incl_scan(int v, int tid, int* wsum) {
  int lane = tid & 63, wave = tid >> 6;
  int s = v;
#pragma unroll
  for (int off = 1; off < 64; off <<= 1) {
    int u = __shfl_up(s, off, 64);
    if (lane >= off) s += u;
  }
  if (lane == 63) wsum[wave] = s;
  __syncthreads();
  int base = 0;
  if (wave > 0) base += wsum[0];
  if (wave > 1) base += wsum[1];
  if (wave > 2) base += wsum[2];
  return base + s;
}

// ---------------------------------------------------------------------------
// Fused prep+partition kernel.
// ---------------------------------------------------------------------------
__global__ __launch_bounds__(256) void prep_part_k(
    const void* __restrict__ ei, int* __restrict__ bcur,
    uint_t* __restrict__ pbuf, uint_t* __restrict__ epk,
    const float* __restrict__ x, ush_t* __restrict__ xb,
    const float* __restrict__ Wl1, const float* __restrict__ Wr1,
    const float* __restrict__ Wl2, const float* __restrict__ Wr2,
    ush_t* __restrict__ Wt1, ush_t* __restrict__ Wt2) {
  __shared__ int hist[256];
  __shared__ int basel[256];
  __shared__ int cur[256];
  __shared__ int gbase[256];
  __shared__ int wsum[4];
  __shared__ uint_t buf[PB];
  __shared__ unsigned char bbuf[PB];
  int tid = threadIdx.x;
  int blk = blockIdx.x;
  if (blk >= PBLK) {
    blk -= PBLK;
    if (blk < PACKB) {  // pack x
      int i = blk * 256 + tid;
      float4 v = reinterpret_cast<const float4*>(x)[i];
      uint2 o;
      o.x = pack2(v.x, v.y);
      o.y = pack2(v.z, v.w);
      reinterpret_cast<uint2*>(xb)[i] = o;
      return;
    }
    blk -= PACKB;  // weight transpose: blk in [0,256)
    int e = blk * 256 + tid;  // < 65536
    int layer = e >> 15;
    int r = e & 32767;
    int col = r >> 8;
    int k = r & 255;
    const float* Wl = layer ? Wl2 : Wl1;
    const float* Wr = layer ? Wr2 : Wr1;
    float v = (k < DD) ? Wl[k * DD + col] : Wr[(k - DD) * DD + col];
    ush_t* Wt = layer ? Wt2 : Wt1;
    Wt[col * 256 + k] = f2bf(v);
    return;
  }
  // ---- partition region ----
  int is64 = detect64(ei);
  hist[tid] = 0;
  __syncthreads();
  long long base = (long long)blk * PB;
  uint_t pv[PB / 256];
#pragma unroll
  for (int i = 0; i < PB / 256; ++i) {
    long long e = base + i * 256 + tid;
    if (e < NE) {
      int s = ld_idx(ei, is64, e);
      int d = ld_idx(ei, is64, (long long)NE + e);
      pv[i] = ((uint_t)(d >> 8) << 24) | ((uint_t)(d & 255) << 16) | (uint_t)s;
      epk[e] = ((uint_t)d << 16) | (uint_t)s;  // original-order compact edges
      atomicAdd(&hist[d >> 8], 1);
    } else {
      pv[i] = 0xFFFFFFFFu;
    }
  }
  __syncthreads();
  int hv = hist[tid];
  int incl = block_incl_scan(hv, tid, wsum);
  basel[tid] = incl - hv;
  cur[tid] = incl - hv;
  if (hv > 0) gbase[tid] = atomicAdd(&bcur[tid], hv);
  __syncthreads();
#pragma unroll
  for (int i = 0; i < PB / 256; ++i) {
    uint_t p = pv[i];
    if (p != 0xFFFFFFFFu) {
      int b = p >> 24;
      int r = atomicAdd(&cur[b], 1);
      buf[r] = p & 0xFFFFFFu;
      bbuf[r] = (unsigned char)b;
    }
  }
  __syncthreads();
  int total = basel[255] + hist[255];
  for (int j = tid; j < total; j += 256) {
    int b = bbuf[j];
    int slot = gbase[b] + (j - basel[b]);
    if (slot < EMAX) pbuf[(size_t)b * EMAX + slot] = buf[j];
  }
}

// ---------------------------------------------------------------------------
// Per-bucket CSR build (one block per bucket), single-CU scatter.
// ---------------------------------------------------------------------------
__global__ __launch_bounds__(256) void csr_k(const uint_t* __restrict__ pbuf,
                                             const int* __restrict__ bcur,
                                             int* __restrict__ offsets,
                                             int* __restrict__ srclist) {
  __shared__ int cnt[256];
  __shared__ int scur[256];
  __shared__ int wsum[4];
  __shared__ int sgb, scnt, stot;
  __shared__ uint_t ebuf[EMAX];
  int tid = threadIdx.x;
  int b = blockIdx.x;
  int v = 0;
  if (tid < BUCKETS) {
    v = bcur[tid];
    if (v > EMAX) v = EMAX;
  }
  int incl = block_incl_scan(v, tid, wsum);
  if (tid == b) { sgb = incl - v; scnt = v; }
  if (tid == BUCKETS - 1) stot = incl;
  cnt[tid] = 0;
  __syncthreads();
  int gb = sgb;
  int ecnt = scnt;
  for (int j = tid; j < ecnt; j += 256) {
    uint_t e = pbuf[(size_t)b * EMAX + j];
    ebuf[j] = e;
    atomicAdd(&cnt[(e >> 16) & 255], 1);
  }
  __syncthreads();
  int c = cnt[tid];
  int incl2 = block_incl_scan(c, tid, wsum);
  int ex = incl2 - c;
  scur[tid] = ex;
  int node = b * 256 + tid;
  if (node < NN) offsets[node] = gb + ex;
  if (b == BUCKETS - 1 && tid == 0) offsets[NN] = stot;
  __syncthreads();
  for (int j = tid; j < ecnt; j += 256) {
    uint_t e = ebuf[j];
    int p = atomicAdd(&scur[(e >> 16) & 255], 1);
    srclist[gb + p] = (int)(e & 0xFFFFu);
  }
}

// ---------------------------------------------------------------------------
// Fused gather-mean + MFMA GEMM core.
// Phase 1: 64 node-means gathered into LDS tile sM (bf16, MPAD-stride rows);
//          16 lanes/node, uint4 loads, unroll x4.
// Phase 2+3: Wt staged in two K-halves (sB = 128 cols x 128 ushorts/half,
//          16 short8 chunks per col -> col = i>>4, cc = i&15 [R10 bug was
//          i>>3/i&7: OOB LDS write + half-staged B => NaN]). Total LDS
//          52.2 KB -> 3 blocks/CU. MFMA half 0 reads A from sM (ds_read),
//          half 1 reads A1 rows straight from global.
// ---------------------------------------------------------------------------
#define AGG_MFMA_CORE(FEATPTR, A1PTR, WTPTR)                                   \
  int tid = threadIdx.x;                                                       \
  int nb = blockIdx.x * 64;                                                    \
  {                                                                            \
    int lane16 = tid & 15;                                                     \
    int ng = tid >> 4;                                                         \
    int f = lane16 << 3;                                                       \
    for (int pass = 0; pass < 4; ++pass) {                                     \
      int ln = pass * 16 + ng;                                                 \
      int node = nb + ln;                                                      \
      float a0 = 0.f, a1v = 0.f, a2 = 0.f, a3 = 0.f,                           \
            a4 = 0.f, a5 = 0.f, a6 = 0.f, a7 = 0.f;                            \
      if (node < NN) {                                                         \
        int beg = offsets[node], end = offsets[node + 1];                      \
        for (int c = beg; c < end; c += 16) {                                  \
          int idx = c + lane16;                                                \
          int sl = (idx < end) ? srclist[idx] : 0;                             \
          int m = min(16, end - c);                                            \
          int jj = 0;                                                          \
          for (; jj + 4 <= m; jj += 4) {                                       \
            int s0 = __shfl(sl, jj, 16);                                       \
            int s1 = __shfl(sl, jj + 1, 16);                                   \
            int s2 = __shfl(sl, jj + 2, 16);                                   \
            int s3 = __shfl(sl, jj + 3, 16);                                   \
            uint4 v0 = *reinterpret_cast<const uint4*>(FEATPTR + (size_t)s0 * DD + f); \
            uint4 v1 = *reinterpret_cast<const uint4*>(FEATPTR + (size_t)s1 * DD + f); \
            uint4 v2 = *reinterpret_cast<const uint4*>(FEATPTR + (size_t)s2 * DD + f); \
            uint4 v3 = *reinterpret_cast<const uint4*>(FEATPTR + (size_t)s3 * DD + f); \
            a0 += bflo(v0.x); a1v += bfhi(v0.x); a2 += bflo(v0.y); a3 += bfhi(v0.y); \
            a4 += bflo(v0.z); a5 += bfhi(v0.z); a6 += bflo(v0.w); a7 += bfhi(v0.w); \
            a0 += bflo(v1.x); a1v += bfhi(v1.x); a2 += bflo(v1.y); a3 += bfhi(v1.y); \
            a4 += bflo(v1.z); a5 += bfhi(v1.z); a6 += bflo(v1.w); a7 += bfhi(v1.w); \
            a0 += bflo(v2.x); a1v += bfhi(v2.x); a2 += bflo(v2.y); a3 += bfhi(v2.y); \
            a4 += bflo(v2.z); a5 += bfhi(v2.z); a6 += bflo(v2.w); a7 += bfhi(v2.w); \
            a0 += bflo(v3.x); a1v += bfhi(v3.x); a2 += bflo(v3.y); a3 += bfhi(v3.y); \
            a4 += bflo(v3.z); a5 += bfhi(v3.z); a6 += bflo(v3.w); a7 += bfhi(v3.w); \
          }                                                                    \
          for (; jj < m; ++jj) {                                               \
            int s = __shfl(sl, jj, 16);                                        \
            uint4 v = *reinterpret_cast<const uint4*>(FEATPTR + (size_t)s * DD + f); \
            a0 += bflo(v.x); a1v += bfhi(v.x); a2 += bflo(v.y); a3 += bfhi(v.y); \
            a4 += bflo(v.z); a5 += bfhi(v.z); a6 += bflo(v.w); a7 += bfhi(v.w); \
          }                                                                    \
        }                                                                      \
        float inv = 1.0f / fmaxf((float)(end - beg), 1.0f);                    \
        a0 *= inv; a1v *= inv; a2 *= inv; a3 *= inv;                           \
        a4 *= inv; a5 *= inv; a6 *= inv; a7 *= inv;                            \
      }                                                                        \
      uint4 o;                                                                 \
      o.x = pack2(a0, a1v); o.y = pack2(a2, a3);                               \
      o.z = pack2(a4, a5);  o.w = pack2(a6, a7);                               \
      *reinterpret_cast<uint4*>(&sM[ln * MPAD + f]) = o;                       \
    }                                                                          \
  }                                                                            \
  int lane = tid & 63;                                                         \
  int wave = tid >> 6;                                                         \
  int n15 = lane & 15, quad = lane >> 4;                                       \
  int row = nb + wave * 16 + n15;                                              \
  int arow = (row < NN) ? row : (NN - 1);                                      \
  const ush_t* a1p = A1PTR + (size_t)arow * DD;                                \
  const ush_t* amp = &sM[(wave * 16 + n15) * MPAD];                            \
  f32x4 acc[8];                                                                \
  _Pragma("unroll")                                                            \
  for (int t = 0; t < 8; ++t) acc[t] = (f32x4){0.f, 0.f, 0.f, 0.f};            \
  for (int h = 0; h < 2; ++h) {                                                \
    __syncthreads();                                                           \
    for (int it = 0; it < 8; ++it) {                                           \
      int i = it * 256 + tid;  /* 0..2047 = 128 cols x 16 chunks */            \
      int col = i >> 4, cc = i & 15;                                           \
      *reinterpret_cast<short8*>(&sB[col * MPAD + cc * 8]) =                   \
          *reinterpret_cast<const short8*>(WTPTR + col * 256 + h * 128 + cc * 8); \
    }                                                                          \
    __syncthreads();                                                           \
    _Pragma("unroll")                                                          \
    for (int c = 0; c < 4; ++c) {                                              \
      int kb = c * 32 + quad * 8;                                              \
      short8 af = (h == 0) ? *reinterpret_cast<const short8*>(&amp[kb])        \
                           : *reinterpret_cast<const short8*>(&a1p[kb]);       \
      _Pragma("unroll")                                                        \
      for (int t = 0; t < 8; ++t) {                                            \
        short8 bf = *reinterpret_cast<const short8*>(&sB[(t * 16 + n15) * MPAD + kb]); \
        acc[t] = __builtin_amdgcn_mfma_f32_16x16x32_bf16(af, bf, acc[t], 0, 0, 0); \
      }                                                                        \
    }                                                                          \
  }

// ---------------------------------------------------------------------------
// Layer 1 fused: mean-gather + h1 = relu([mean||x] @ Wt1 + bl1), bf16 out.
// ---------------------------------------------------------------------------
__global__ __launch_bounds__(256, 3) void agg_sage_l1(
    const ush_t* __restrict__ xb, const int* __restrict__ srclist,
    const int* __restrict__ offsets, const ush_t* __restrict__ Wt1,
    const float* __restrict__ bl, ush_t* __restrict__ h1b) {
  __shared__ __align__(16) ush_t sM[64 * MPAD];
  __shared__ __align__(16) ush_t sB[128 * MPAD];
  AGG_MFMA_CORE(xb, xb, Wt1)
#pragma unroll
  for (int t = 0; t < 8; ++t) {
    int col = t * 16 + n15;
    float b = bl[col];
#pragma unroll
    for (int reg = 0; reg < 4; ++reg) {
      int r = nb + wave * 16 + quad * 4 + reg;
      if (r < NN)
        h1b[(size_t)r * DD + col] = f2bf(fmaxf(acc[t][reg] + b, 0.f));
    }
  }
}

// ---------------------------------------------------------------------------
// Layer 2 fused: mean-gather over h1 + edge projection epilogue.
// ---------------------------------------------------------------------------
__global__ __launch_bounds__(256, 3) void agg_sage_l2(
    const ush_t* __restrict__ h1b, const int* __restrict__ srclist,
    const int* __restrict__ offsets, const ush_t* __restrict__ Wt2,
    const float* __restrict__ bl, const float* __restrict__ We,
    float2* __restrict__ s12) {
  __shared__ __align__(16) ush_t sM[64 * MPAD];
  __shared__ __align__(16) ush_t sB[128 * MPAD];
  AGG_MFMA_CORE(h1b, h1b, Wt2)
  float p1[4] = {0.f, 0.f, 0.f, 0.f};
  float p2[4] = {0.f, 0.f, 0.f, 0.f};
#pragma unroll
  for (int t = 0; t < 8; ++t) {
    int col = t * 16 + n15;
    float b = bl[col];
    float w1 = We[col];
    float w2 = We[DD + col];
#pragma unroll
    for (int reg = 0; reg < 4; ++reg) {
      float v = acc[t][reg] + b;
      p1[reg] += v * w1;
      p2[reg] += v * w2;
    }
  }
#pragma unroll
  for (int reg = 0; reg < 4; ++reg) {
    float v1 = p1[reg], v2 = p2[reg];
    for (int off = 8; off > 0; off >>= 1) {
      v1 += __shfl_down(v1, off, 16);
      v2 += __shfl_down(v2, off, 16);
    }
    int r = nb + wave * 16 + quad * 4 + reg;
    if (n15 == 0 && r < NN) s12[r] = make_float2(v1, v2);
  }
}

// ---------------------------------------------------------------------------
// Edge scores from compact edges: y = sigmoid(s1[src] + s2[tgt] + be).
// ---------------------------------------------------------------------------
__global__ __launch_bounds__(256) void edge_k(const uint_t* __restrict__ epk,
                                              const float2* __restrict__ s12,
                                              const float* __restrict__ be,
                                              float* __restrict__ out) {
  int e = blockIdx.x * 256 + threadIdx.x;
  uint_t p = epk[e];
  float2 a = s12[p & 0xFFFFu];   // src -> s1
  float2 b = s12[p >> 16];       // tgt -> s2
  float v = a.x + b.y + be[0];
  out[e] = 1.0f / (1.0f + __expf(-v));
}

extern "C" void kernel_launch(void* const* d_in, const int* in_sizes, int n_in,
                              void* d_out, int out_size, void* d_ws, size_t ws_size,
                              hipStream_t stream) {
  const float* x   = (const float*)d_in[0];
  const void*  ei  = d_in[1];
  const float* Wl1 = (const float*)d_in[2];
  const float* bl1 = (const float*)d_in[3];
  const float* Wr1 = (const float*)d_in[4];
  const float* Wl2 = (const float*)d_in[5];
  const float* bl2 = (const float*)d_in[6];
  const float* Wr2 = (const float*)d_in[7];
  const float* We  = (const float*)d_in[8];
  const float* be  = (const float*)d_in[9];
  float* out = (float*)d_out;

  // Workspace (4B units, sections 16B-aligned):
  // bcur[256] | offsets[50004] | epk[NE] | pbuf[BUCKETS*EMAX] | srclist[NE] |
  // xb[NN*DD/2] | h1b[NN*DD/2] | s12[2*NN] | Wt1[16384] | Wt2[16384]
  int* bcur    = (int*)d_ws;
  int* offsets = bcur + 256;
  uint_t* epk  = (uint_t*)(offsets + 50004);
  uint_t* pbuf = epk + NE;
  int* srclist = (int*)(pbuf + (size_t)BUCKETS * EMAX);
  ush_t* xb    = (ush_t*)(srclist + NE);
  ush_t* h1b   = xb + (size_t)NN * DD;
  float2* s12  = (float2*)(h1b + (size_t)NN * DD);
  ush_t* Wt1   = (ush_t*)((float*)s12 + 2 * NN);
  ush_t* Wt2   = Wt1 + 32768;

  hipMemsetAsync(bcur, 0, 256 * sizeof(int), stream);
  prep_part_k<<<PBLK + PACKB + 256, 256, 0, stream>>>(
      ei, bcur, pbuf, epk, x, xb, Wl1, Wr1, Wl2, Wr2, Wt1, Wt2);
  csr_k<<<BUCKETS, 256, 0, stream>>>(pbuf, bcur, offsets, srclist);

  int gemm_blocks = (NN + 63) / 64;  // 782
  agg_sage_l1<<<gemm_blocks, 256, 0, stream>>>(xb, srclist, offsets, Wt1, bl1, h1b);
  agg_sage_l2<<<gemm_blocks, 256, 0, stream>>>(h1b, srclist, offsets, Wt2, bl2, We, s12);

  edge_k<<<NE / 256, 256, 0, stream>>>(epk, s12, be, out);
}